// Round 14
// baseline (269.996 us; speedup 1.0000x reference)
//
#include <hip/hip_runtime.h>

typedef unsigned short u16;
typedef unsigned int u32;
typedef unsigned long long u64;
typedef __attribute__((ext_vector_type(8))) short short8;
typedef __attribute__((ext_vector_type(4))) float f32x4;
typedef __attribute__((ext_vector_type(16))) float f32x16;
typedef __attribute__((ext_vector_type(4))) u32 u32x4;

constexpr int S_LEN = 2048;
constexpr int DMODEL = 1024;

#if __has_builtin(__builtin_amdgcn_exp2f)
#define EXP2 __builtin_amdgcn_exp2f
#else
#define EXP2 exp2f
#endif

__device__ __forceinline__ u16 f2bf(float f) {
  u32 u = __builtin_bit_cast(u32, f);
  u += 0x7FFFu + ((u >> 16) & 1u);   // RNE
  return (u16)(u >> 16);
}

__device__ __forceinline__ u32 cvtpk(float a, float b) {
  u32 r;
  asm("v_cvt_pk_bf16_f32 %0, %1, %2" : "=v"(r) : "v"(a), "v"(b));
  return r;
}

// v_permlane32_swap_b32 a, b:
//   a' = (lane<32) ? a[lane] : b[lane-32]
//   b' = (lane<32) ? a[lane+32] : b[lane]
__device__ __forceinline__ void plswap(u32& a, u32& b) {
  asm("v_permlane32_swap_b32 %0, %1" : "+v"(a), "+v"(b));
}

__device__ __forceinline__ void gload_lds16(const void* g, void* l) {
  __builtin_amdgcn_global_load_lds((const __attribute__((address_space(1))) u32*)g,
                                   (__attribute__((address_space(3))) u32*)l,
                                   16, 0, 0);
}

// ---- prep: fp32->bf16 weight convert (y=0..3) + mask bit-pack (y=4) ----
__global__ __launch_bounds__(256) void prep_kernel(
    const float* __restrict__ w0, const float* __restrict__ w1,
    const float* __restrict__ w2, const float* __restrict__ w3,
    u16* __restrict__ o0, u16* __restrict__ o1,
    u16* __restrict__ o2, u16* __restrict__ o3,
    const int* __restrict__ mask, u64* __restrict__ mb) {
  if (blockIdx.y == 4) {
    int gw = (blockIdx.x * 256 + threadIdx.x) >> 6;
    int lane = threadIdx.x & 63;
    #pragma unroll
    for (int i = 0; i < 16; ++i) {
      size_t word = (size_t)gw * 16 + i;
      int m = mask[word * 64 + lane];
      u64 bits = __ballot(m != 0);
      if (lane == 0) mb[word] = bits;
    }
    return;
  }
  const float* src; u16* dst;
  switch (blockIdx.y) {
    case 0: src = w0; dst = o0; break;
    case 1: src = w1; dst = o1; break;
    case 2: src = w2; dst = o2; break;
    default: src = w3; dst = o3; break;
  }
  int i = blockIdx.x * 256 + threadIdx.x;
  float4 v = ((const float4*)src)[i];
  ushort4 h;
  h.x = f2bf(v.x); h.y = f2bf(v.y); h.z = f2bf(v.z); h.w = f2bf(v.w);
  ((ushort4*)dst)[i] = h;
}

// ---- GEMM: C[m,n] = (sum_k A[m,k] * W[n,k] + bias[n]) * scale ----
// A either fp32 (AF32: staged raw to LDS via pre-swizzled gload_lds, converted
// to bf16 during fragment read) or bf16 (linear gload_lds path).
// fp32 A-tile [128 rows][32 f32]: 128B rows would be a 16-way bank conflict on
// fragment reads; XOR-swizzle 16B-slot index with (row&7), applied to the
// GLOBAL source on staging (m173: gload_lds dest must stay linear) and to the
// LDS byte offset on read (same involution both sides).
// OM: 0 = bf16 row-major, 1 = fp32 row-major, 2 = bf16 transposed-V layout
template<int OM, bool AF32>
__global__ __launch_bounds__(256) void gemm_bt_kernel(
    const void* __restrict__ Av, const u16* __restrict__ W,
    const float* __restrict__ bias, void* __restrict__ Cv, float scale) {
  constexpr int BK = 32;
  __shared__ __align__(16) char Araw[AF32 ? 128 * BK * 4 : 128 * BK * 2];
  __shared__ __align__(16) u16 Bs[128 * BK];
  const int tid = threadIdx.x;
  const int lane = tid & 63, w = tid >> 6;
  const int l15 = lane & 15, lg = lane >> 4;
  const int m0 = blockIdx.x * 128, n0 = blockIdx.y * 128;
  const int wm = w >> 1, wn = w & 1;
  f32x4 acc[4][4] = {};

  for (int kt = 0; kt < 1024; kt += BK) {
    #pragma unroll
    for (int j = 0; j < 2; ++j) {
      int sb = (w * 2 + j) * 64;
      int slot = sb + lane;
      int row = slot >> 2, c8 = slot & 3;
      gload_lds16(W + (size_t)(n0 + row) * 1024 + kt + c8 * 8,
                  Bs + (size_t)sb * 8);
    }
    if constexpr (AF32) {
      const float* Af = (const float*)Av;
      #pragma unroll
      for (int i = 0; i < 4; ++i) {
        int g = tid + i * 256;              // 1024 slots of 16B
        int row = g >> 3;
        int off16 = (g & 7) ^ (row & 7);    // pre-swizzled source slot
        gload_lds16(Af + (size_t)(m0 + row) * 1024 + kt + off16 * 4,
                    Araw + (size_t)g * 16);
      }
    } else {
      const u16* Ab = (const u16*)Av;
      #pragma unroll
      for (int j = 0; j < 2; ++j) {
        int sb = (w * 2 + j) * 64;
        int slot = sb + lane;
        int row = slot >> 2, c8 = slot & 3;
        gload_lds16(Ab + (size_t)(m0 + row) * 1024 + kt + c8 * 8,
                    Araw + (size_t)slot * 16);
      }
    }
    __syncthreads();
    short8 af[4], bfr[4];
    #pragma unroll
    for (int m = 0; m < 4; ++m) {
      int row = wm * 64 + m * 16 + l15;
      if constexpr (AF32) {
        const char* rp = Araw + row * 128;
        float4 fa0 = *(const float4*)(rp + ((lg * 32) ^ ((row & 7) << 4)));
        float4 fa1 = *(const float4*)(rp + ((lg * 32 + 16) ^ ((row & 7) << 4)));
        u32x4 pw;
        pw.x = cvtpk(fa0.x, fa0.y); pw.y = cvtpk(fa0.z, fa0.w);
        pw.z = cvtpk(fa1.x, fa1.y); pw.w = cvtpk(fa1.z, fa1.w);
        af[m] = __builtin_bit_cast(short8, pw);
      } else {
        af[m] = *(const short8*)&((const u16*)Araw)[row * BK + lg * 8];
      }
    }
    #pragma unroll
    for (int n = 0; n < 4; ++n)
      bfr[n] = *(const short8*)&Bs[(wn * 64 + n * 16 + l15) * BK + lg * 8];
    #pragma unroll
    for (int m = 0; m < 4; ++m)
      #pragma unroll
      for (int n = 0; n < 4; ++n)
        acc[m][n] = __builtin_amdgcn_mfma_f32_16x16x32_bf16(af[m], bfr[n], acc[m][n], 0, 0, 0);
    __syncthreads();
  }

  #pragma unroll
  for (int m = 0; m < 4; ++m) {
    #pragma unroll
    for (int n = 0; n < 4; ++n) {
      int col = n0 + wn * 64 + n * 16 + l15;
      float bcol = bias[col];
      int row0 = m0 + wm * 64 + m * 16 + lg * 4;
      if constexpr (OM == 2) {
        // transposed-V store: 4 consecutive s for one (b,h,d) row
        int b = row0 >> 11, s = row0 & 2047;
        ushort4 o;
        o.x = f2bf((acc[m][n][0] + bcol) * scale);
        o.y = f2bf((acc[m][n][1] + bcol) * scale);
        o.z = f2bf((acc[m][n][2] + bcol) * scale);
        o.w = f2bf((acc[m][n][3] + bcol) * scale);
        u16* dst = (u16*)Cv + ((size_t)(b * 16 + (col >> 6)) * 64 + (col & 63)) * S_LEN + s;
        *(ushort4*)dst = o;
      } else {
        #pragma unroll
        for (int r = 0; r < 4; ++r) {
          float v = (acc[m][n][r] + bcol) * scale;
          if constexpr (OM == 1)
            ((float*)Cv)[(size_t)(row0 + r) * 1024 + col] = v;
          else
            ((u16*)Cv)[(size_t)(row0 + r) * 1024 + col] = f2bf(v);
        }
      }
    }
  }
}

// ---- flash attention, swapped-operand 32x32, static-max softmax ----
// 8 waves/block (512 thr), 32 q/wave = 256 q/block, 512 blocks -> 2 blocks/CU,
// 16 waves/CU. K/V staged once per 256 q (half the stage traffic of the 4-wave
// version); per-wave code identical to the proven round-5 form (VGPR ~64, no
// spill headroom issues; do NOT grow per-wave live state — see round-8/10).
__global__ __launch_bounds__(512, 4) void attn_kernel(
    const u16* __restrict__ Qp, const u16* __restrict__ Kp,
    const u16* __restrict__ VpT, const u64* __restrict__ mb,
    u16* __restrict__ X) {
  constexpr float NEGL2 = -1.4426950e9f;
  __shared__ __align__(16) u16 Ks[2][4096];    // [k][d] XOR-swizzled rows
  __shared__ __align__(16) u16 VTs[2][4096];   // [d][k] XOR-swizzled rows
  const int tid = threadIdx.x;
  const int lane = tid & 63, w = tid >> 6;     // w = 0..7
  const int l31 = lane & 31, hi1 = lane >> 5;

  // XCD-aware block swizzle: 512 blocks -> 8 chunks of 64
  u32 id = blockIdx.x;
  u32 nid = ((id & 7) << 6) | (id >> 3);
  const int bh = nid >> 3, qt = nid & 7;
  const int b = bh >> 4, h = bh & 15;
  const size_t bS = (size_t)b * S_LEN;
  const int wq0 = qt * 256 + w * 32;

  // Q fragment (B-operand): lane holds Q[q=wq0+l31][d = dk*16 + hi1*8 + j]
  short8 qf[4];
  {
    const u16* qb = Qp + (bS + wq0 + l31) * DMODEL + h * 64;
    #pragma unroll
    for (int dk = 0; dk < 4; ++dk)
      qf[dk] = *(const short8*)(qb + dk * 16 + hi1 * 8);
  }

  f32x16 xacc[2] = {};
  float lsum = 0.f;

  auto stage = [&](int k0, int nb) {
    {                                   // K tile [64 k][64 d]: 512 slots
      int g = tid;
      int kk = g >> 3, dh = g & 7;
      gload_lds16(Kp + (bS + k0 + kk) * DMODEL + h * 64 + ((dh ^ (kk & 7)) << 3),
                  (char*)&Ks[nb][0] + g * 16);
    }
    {                                   // V^T tile [64 d][64 k]: 512 slots
      int g = tid;
      int dd = g >> 3, kh = g & 7;
      gload_lds16(VpT + ((size_t)(bh * 64 + dd)) * S_LEN + k0 + ((kh ^ (dd & 7)) << 3),
                  (char*)&VTs[nb][0] + g * 16);
    }
  };

  stage(0, 0);
  __syncthreads();

  constexpr int NT = S_LEN / 64;
  for (int t = 0; t < NT; ++t) {
    const int cur = t & 1;
    if (t + 1 < NT) stage((t + 1) * 64, cur ^ 1);

    // ---- QK^T: ST[k][q] - 16, 2 chunks of 32 k ----
    f32x16 c0, c1;
    #pragma unroll
    for (int r = 0; r < 16; ++r) { c0[r] = -16.f; c1[r] = -16.f; }
    const u16* ksp = &Ks[cur][0];
    __builtin_amdgcn_s_setprio(1);
    #pragma unroll
    for (int dk = 0; dk < 4; ++dk) {
      short8 a0 = *(const short8*)&ksp[((l31) * 64 + dk * 16 + hi1 * 8) ^ ((l31 & 7) << 3)];
      short8 a1 = *(const short8*)&ksp[((32 + l31) * 64 + dk * 16 + hi1 * 8) ^ ((l31 & 7) << 3)];
      c0 = __builtin_amdgcn_mfma_f32_32x32x16_bf16(a0, qf[dk], c0, 0, 0, 0);
      c1 = __builtin_amdgcn_mfma_f32_32x32x16_bf16(a1, qf[dk], c1, 0, 0, 0);
    }
    __builtin_amdgcn_s_setprio(0);

    // ---- mask (register r holds k = (r&3) + 8*(r>>2) + 4*hi1 [+32 for c1]) ----
    u64 mw = mb[(size_t)(wq0 + l31) * 32 + t];
    bool allone = __all((long long)mw == -1LL);
    if (!allone) {
      #pragma unroll
      for (int r = 0; r < 16; ++r) {
        int k0i = (r & 3) + 8 * (r >> 2) + 4 * hi1;
        c0[r] = ((mw >> k0i) & 1) ? c0[r] : NEGL2;
        c1[r] = ((mw >> (k0i + 32)) & 1) ? c1[r] : NEGL2;
      }
    }

    // ---- static-max softmax: p = 2^(s-16); 2-way partial sums (short chains) ----
    float lsa = 0.f, lsb = 0.f;
    #pragma unroll
    for (int r = 0; r < 16; ++r) {
      float p = EXP2(c0[r]); c0[r] = p;
      if (r & 1) lsb += p; else lsa += p;
    }
    #pragma unroll
    for (int r = 0; r < 16; ++r) {
      float p = EXP2(c1[r]); c1[r] = p;
      if (r & 1) lsb += p; else lsa += p;
    }
    lsum += lsa + lsb;

    // ---- pack P to bf16 word-pairs ----
    u32 Wp[2][8];
    #pragma unroll
    for (int i = 0; i < 8; ++i) {
      Wp[0][i] = cvtpk(c0[2 * i], c0[2 * i + 1]);
      Wp[1][i] = cvtpk(c1[2 * i], c1[2 * i + 1]);
    }

    // ---- PV: xacc[dt] += V^T(frag) * P^T(frag), 4 k-slices of 16 ----
    const u16* vtp = &VTs[cur][0];
    __builtin_amdgcn_s_setprio(1);
    #pragma unroll
    for (int ks16 = 0; ks16 < 4; ++ks16) {
      const int kc = ks16 >> 1, ks = ks16 & 1;
      // B-fragment: lane (q=l31, hi1) needs P[q][ks16*16 + hi1*8 + j]
      u32 wa0 = Wp[kc][ks * 4 + 0], wb0 = Wp[kc][ks * 4 + 2];
      u32 wa1 = Wp[kc][ks * 4 + 1], wb1 = Wp[kc][ks * 4 + 3];
      plswap(wa0, wb0);   // wa0 = word01, wb0 = word45 (per-lane correct halves)
      plswap(wa1, wb1);
      u32x4 pw; pw.x = wa0; pw.y = wa1; pw.z = wb0; pw.w = wb1;
      short8 pfrag = __builtin_bit_cast(short8, pw);
      #pragma unroll
      for (int dt = 0; dt < 2; ++dt) {
        int d = dt * 32 + l31;
        short8 vf = *(const short8*)&vtp[(d * 64 + ks16 * 16 + hi1 * 8) ^ ((d & 7) << 3)];
        xacc[dt] = __builtin_amdgcn_mfma_f32_32x32x16_bf16(vf, pfrag, xacc[dt], 0, 0, 0);
      }
    }
    __builtin_amdgcn_s_setprio(0);
    __syncthreads();
  }

  // ---- normalize + store: lane holds X^T[d = dt*32 + crow(r,hi1)][q = wq0+l31] ----
  lsum += __shfl_xor(lsum, 32);
  float inv = 1.0f / lsum;
  u16* xb = X + (bS + wq0 + l31) * DMODEL + h * 64;
  #pragma unroll
  for (int dt = 0; dt < 2; ++dt)
    #pragma unroll
    for (int m = 0; m < 4; ++m) {
      ushort4 o;
      o.x = f2bf(xacc[dt][m * 4 + 0] * inv);
      o.y = f2bf(xacc[dt][m * 4 + 1] * inv);
      o.z = f2bf(xacc[dt][m * 4 + 2] * inv);
      o.w = f2bf(xacc[dt][m * 4 + 3] * inv);
      *(ushort4*)(xb + dt * 32 + m * 8 + hi1 * 4) = o;
    }
}

extern "C" void kernel_launch(void* const* d_in, const int* in_sizes, int n_in,
                              void* d_out, int out_size, void* d_ws, size_t ws_size,
                              hipStream_t stream) {
  const float* q  = (const float*)d_in[0];
  const float* k  = (const float*)d_in[1];
  const float* v  = (const float*)d_in[2];
  const int* mask = (const int*)d_in[3];
  const float* wq = (const float*)d_in[4];
  const float* bq = (const float*)d_in[5];
  const float* wk = (const float*)d_in[6];
  const float* bk = (const float*)d_in[7];
  const float* wv = (const float*)d_in[8];
  const float* bv = (const float*)d_in[9];
  const float* wo = (const float*)d_in[10];
  const float* bo = (const float*)d_in[11];

  char* ws = (char*)d_ws;
  u16* wqb = (u16*)(ws + 0x000000);
  u16* wkb = (u16*)(ws + 0x200000);
  u16* wvb = (u16*)(ws + 0x400000);
  u16* wob = (u16*)(ws + 0x600000);
  u64* mbp = (u64*)(ws + 0x800000);
  u16* Qp  = (u16*)(ws + 0x880000);
  u16* Kp  = (u16*)(ws + 0x1880000);
  u16* Xp  = (u16*)(ws + 0x3880000);   // attn output
  u16* VpT = (u16*)(ws + 0x4880000);   // end 0x5880000 = 92.7 MB

  const float QSCALE = 0.125f * 1.44269504088896340736f;  // fold 1/sqrt(64) * log2(e)

  prep_kernel<<<dim3(1024, 5), 256, 0, stream>>>(wq, wk, wv, wo, wqb, wkb, wvb, wob,
                                                 mask, mbp);

  gemm_bt_kernel<2, true><<<dim3(64, 8), 256, 0, stream>>>(v, wvb, bv, VpT, 1.0f);
  gemm_bt_kernel<0, true><<<dim3(64, 8), 256, 0, stream>>>(k, wkb, bk, Kp, 1.0f);
  gemm_bt_kernel<0, true><<<dim3(64, 8), 256, 0, stream>>>(q, wqb, bq, Qp, QSCALE);

  attn_kernel<<<512, 512, 0, stream>>>(Qp, Kp, VpT, mbp, Xp);
  gemm_bt_kernel<1, false><<<dim3(64, 8), 256, 0, stream>>>(Xp, wob, bo, (float*)d_out, 1.0f);
}

// Round 15
// 235.386 us; speedup vs baseline: 1.1470x; 1.1470x over previous
//
#include <hip/hip_runtime.h>

typedef unsigned short u16;
typedef unsigned int u32;
typedef unsigned long long u64;
typedef __attribute__((ext_vector_type(8))) short short8;
typedef __attribute__((ext_vector_type(4))) float f32x4;
typedef __attribute__((ext_vector_type(16))) float f32x16;
typedef __attribute__((ext_vector_type(4))) u32 u32x4;

constexpr int S_LEN = 2048;
constexpr int DMODEL = 1024;

#if __has_builtin(__builtin_amdgcn_exp2f)
#define EXP2 __builtin_amdgcn_exp2f
#else
#define EXP2 exp2f
#endif

__device__ __forceinline__ u16 f2bf(float f) {
  u32 u = __builtin_bit_cast(u32, f);
  u += 0x7FFFu + ((u >> 16) & 1u);   // RNE
  return (u16)(u >> 16);
}

__device__ __forceinline__ u32 cvtpk(float a, float b) {
  u32 r;
  asm("v_cvt_pk_bf16_f32 %0, %1, %2" : "=v"(r) : "v"(a), "v"(b));
  return r;
}

// v_permlane32_swap_b32 a, b:
//   a' = (lane<32) ? a[lane] : b[lane-32]
//   b' = (lane<32) ? a[lane+32] : b[lane]
__device__ __forceinline__ void plswap(u32& a, u32& b) {
  asm("v_permlane32_swap_b32 %0, %1" : "+v"(a), "+v"(b));
}

__device__ __forceinline__ void gload_lds16(const void* g, void* l) {
  __builtin_amdgcn_global_load_lds((const __attribute__((address_space(1))) u32*)g,
                                   (__attribute__((address_space(3))) u32*)l,
                                   16, 0, 0);
}

// ---- prep: fp32->bf16 weight convert (y=0..3) + mask bit-pack (y=4) ----
__global__ __launch_bounds__(256) void prep_kernel(
    const float* __restrict__ w0, const float* __restrict__ w1,
    const float* __restrict__ w2, const float* __restrict__ w3,
    u16* __restrict__ o0, u16* __restrict__ o1,
    u16* __restrict__ o2, u16* __restrict__ o3,
    const int* __restrict__ mask, u64* __restrict__ mb) {
  if (blockIdx.y == 4) {
    int gw = (blockIdx.x * 256 + threadIdx.x) >> 6;
    int lane = threadIdx.x & 63;
    #pragma unroll
    for (int i = 0; i < 16; ++i) {
      size_t word = (size_t)gw * 16 + i;
      int m = mask[word * 64 + lane];
      u64 bits = __ballot(m != 0);
      if (lane == 0) mb[word] = bits;
    }
    return;
  }
  const float* src; u16* dst;
  switch (blockIdx.y) {
    case 0: src = w0; dst = o0; break;
    case 1: src = w1; dst = o1; break;
    case 2: src = w2; dst = o2; break;
    default: src = w3; dst = o3; break;
  }
  int i = blockIdx.x * 256 + threadIdx.x;
  float4 v = ((const float4*)src)[i];
  ushort4 h;
  h.x = f2bf(v.x); h.y = f2bf(v.y); h.z = f2bf(v.z); h.w = f2bf(v.w);
  ((ushort4*)dst)[i] = h;
}

// ---- fp32 -> bf16 activation convert, 3 tensors in one launch ----
__global__ __launch_bounds__(256) void cvt_a3_kernel(
    const float* __restrict__ s0, const float* __restrict__ s1,
    const float* __restrict__ s2,
    u16* __restrict__ d0, u16* __restrict__ d1, u16* __restrict__ d2) {
  const float* src; u16* dst;
  switch (blockIdx.y) {
    case 0: src = s0; dst = d0; break;
    case 1: src = s1; dst = d1; break;
    default: src = s2; dst = d2; break;
  }
  int i = blockIdx.x * 256 + threadIdx.x;   // 2,097,152 float4s per tensor
  float4 v = ((const float4*)src)[i];
  ushort4 h;
  h.x = f2bf(v.x); h.y = f2bf(v.y); h.z = f2bf(v.z); h.w = f2bf(v.w);
  ((ushort4*)dst)[i] = h;
}

// ---- merged projection GEMMs: z=0 V (transposed-V store), z=1 K, z=2 Q ----
// C[m,n] = (sum_k A[m,k]*W[n,k] + bias[n]) * scale; A bf16, proven round-7
// body (single LDS buffer, two barriers per K-step). 1536 blocks = 6/CU.
__global__ __launch_bounds__(256) void gemm_proj3_kernel(
    const u16* __restrict__ av, const u16* __restrict__ ak, const u16* __restrict__ aq,
    const u16* __restrict__ wvb, const u16* __restrict__ wkb, const u16* __restrict__ wqb,
    const float* __restrict__ bv, const float* __restrict__ bk, const float* __restrict__ bq,
    u16* __restrict__ vpt, u16* __restrict__ kp, u16* __restrict__ qp, float qscale) {
  constexpr int BK = 32;
  __shared__ __align__(16) u16 As[128 * BK];
  __shared__ __align__(16) u16 Bs[128 * BK];
  const int z = blockIdx.z;
  const u16* A = (z == 0) ? av : (z == 1) ? ak : aq;
  const u16* W = (z == 0) ? wvb : (z == 1) ? wkb : wqb;
  const float* bias = (z == 0) ? bv : (z == 1) ? bk : bq;
  const float scale = (z == 2) ? qscale : 1.0f;
  const int tid = threadIdx.x;
  const int lane = tid & 63, w = tid >> 6;
  const int l15 = lane & 15, lg = lane >> 4;
  const int m0 = blockIdx.x * 128, n0 = blockIdx.y * 128;
  const int wm = w >> 1, wn = w & 1;
  f32x4 acc[4][4] = {};

  for (int kt = 0; kt < 1024; kt += BK) {
    #pragma unroll
    for (int j = 0; j < 2; ++j) {
      int sb = (w * 2 + j) * 64;
      int slot = sb + lane;
      int row = slot >> 2, c8 = slot & 3;
      gload_lds16(W + (size_t)(n0 + row) * 1024 + kt + c8 * 8,
                  (char*)Bs + (size_t)sb * 16);
      gload_lds16(A + (size_t)(m0 + row) * 1024 + kt + c8 * 8,
                  (char*)As + (size_t)sb * 16);
    }
    __syncthreads();
    short8 af[4], bfr[4];
    #pragma unroll
    for (int m = 0; m < 4; ++m)
      af[m] = *(const short8*)&As[(wm * 64 + m * 16 + l15) * BK + lg * 8];
    #pragma unroll
    for (int n = 0; n < 4; ++n)
      bfr[n] = *(const short8*)&Bs[(wn * 64 + n * 16 + l15) * BK + lg * 8];
    #pragma unroll
    for (int m = 0; m < 4; ++m)
      #pragma unroll
      for (int n = 0; n < 4; ++n)
        acc[m][n] = __builtin_amdgcn_mfma_f32_16x16x32_bf16(af[m], bfr[n], acc[m][n], 0, 0, 0);
    __syncthreads();
  }

  #pragma unroll
  for (int m = 0; m < 4; ++m) {
    #pragma unroll
    for (int n = 0; n < 4; ++n) {
      int col = n0 + wn * 64 + n * 16 + l15;
      float bcol = bias[col];
      int row0 = m0 + wm * 64 + m * 16 + lg * 4;
      if (z == 0) {
        // transposed-V store: VpT[(b*16+h)*64+d][s], 4 consecutive s
        int b = row0 >> 11, s = row0 & 2047;
        ushort4 o;
        o.x = f2bf(acc[m][n][0] + bcol);
        o.y = f2bf(acc[m][n][1] + bcol);
        o.z = f2bf(acc[m][n][2] + bcol);
        o.w = f2bf(acc[m][n][3] + bcol);
        u16* dst = vpt + ((size_t)(b * 16 + (col >> 6)) * 64 + (col & 63)) * S_LEN + s;
        *(ushort4*)dst = o;
      } else {
        u16* C = (z == 1) ? kp : qp;
        #pragma unroll
        for (int r = 0; r < 4; ++r)
          C[(size_t)(row0 + r) * 1024 + col] = f2bf((acc[m][n][r] + bcol) * scale);
      }
    }
  }
}

// ---- final output GEMM: fp32 row-major out ----
__global__ __launch_bounds__(256) void gemm_out_kernel(
    const u16* __restrict__ A, const u16* __restrict__ W,
    const float* __restrict__ bias, float* __restrict__ C) {
  constexpr int BK = 32;
  __shared__ __align__(16) u16 As[128 * BK];
  __shared__ __align__(16) u16 Bs[128 * BK];
  const int tid = threadIdx.x;
  const int lane = tid & 63, w = tid >> 6;
  const int l15 = lane & 15, lg = lane >> 4;
  const int m0 = blockIdx.x * 128, n0 = blockIdx.y * 128;
  const int wm = w >> 1, wn = w & 1;
  f32x4 acc[4][4] = {};

  for (int kt = 0; kt < 1024; kt += BK) {
    #pragma unroll
    for (int j = 0; j < 2; ++j) {
      int sb = (w * 2 + j) * 64;
      int slot = sb + lane;
      int row = slot >> 2, c8 = slot & 3;
      gload_lds16(W + (size_t)(n0 + row) * 1024 + kt + c8 * 8,
                  (char*)Bs + (size_t)sb * 16);
      gload_lds16(A + (size_t)(m0 + row) * 1024 + kt + c8 * 8,
                  (char*)As + (size_t)sb * 16);
    }
    __syncthreads();
    short8 af[4], bfr[4];
    #pragma unroll
    for (int m = 0; m < 4; ++m)
      af[m] = *(const short8*)&As[(wm * 64 + m * 16 + l15) * BK + lg * 8];
    #pragma unroll
    for (int n = 0; n < 4; ++n)
      bfr[n] = *(const short8*)&Bs[(wn * 64 + n * 16 + l15) * BK + lg * 8];
    #pragma unroll
    for (int m = 0; m < 4; ++m)
      #pragma unroll
      for (int n = 0; n < 4; ++n)
        acc[m][n] = __builtin_amdgcn_mfma_f32_16x16x32_bf16(af[m], bfr[n], acc[m][n], 0, 0, 0);
    __syncthreads();
  }

  #pragma unroll
  for (int m = 0; m < 4; ++m) {
    #pragma unroll
    for (int n = 0; n < 4; ++n) {
      int col = n0 + wn * 64 + n * 16 + l15;
      float bcol = bias[col];
      int row0 = m0 + wm * 64 + m * 16 + lg * 4;
      #pragma unroll
      for (int r = 0; r < 4; ++r)
        C[(size_t)(row0 + r) * 1024 + col] = acc[m][n][r] + bcol;
    }
  }
}

// ---- flash attention, swapped-operand 32x32, static-max softmax ----
// Round-5/11 proven form (100 µs, VGPR 64, no spill): 32 q/wave, 128 q/block,
// 1024 blocks (~4 blocks/CU). Register budget ≈110 < 128 cap — do NOT grow
// per-wave live state (round-8/10 split spilled); 8-wave blocks regress
// (round 14: 106 µs, barrier cost > occupancy gain).
__global__ __launch_bounds__(256, 4) void attn_kernel(
    const u16* __restrict__ Qp, const u16* __restrict__ Kp,
    const u16* __restrict__ VpT, const u64* __restrict__ mb,
    u16* __restrict__ X) {
  constexpr float NEGL2 = -1.4426950e9f;
  __shared__ __align__(16) u16 Ks[2][4096];    // [k][d] XOR-swizzled rows
  __shared__ __align__(16) u16 VTs[2][4096];   // [d][k] XOR-swizzled rows
  const int tid = threadIdx.x;
  const int lane = tid & 63, w = tid >> 6;
  const int l31 = lane & 31, hi1 = lane >> 5;

  // XCD-aware block swizzle: 1024 blocks -> 8 chunks of 128
  u32 id = blockIdx.x;
  u32 nid = ((id & 7) << 7) | (id >> 3);
  const int bh = nid >> 4, qt = nid & 15;
  const int b = bh >> 4, h = bh & 15;
  const size_t bS = (size_t)b * S_LEN;
  const int wq0 = qt * 128 + w * 32;

  // Q fragment (B-operand): lane holds Q[q=wq0+l31][d = dk*16 + hi1*8 + j]
  short8 qf[4];
  {
    const u16* qb = Qp + (bS + wq0 + l31) * DMODEL + h * 64;
    #pragma unroll
    for (int dk = 0; dk < 4; ++dk)
      qf[dk] = *(const short8*)(qb + dk * 16 + hi1 * 8);
  }

  f32x16 xacc[2] = {};
  float lsum = 0.f;

  auto stage = [&](int k0, int nb) {
    #pragma unroll
    for (int i = 0; i < 2; ++i) {       // K tile [64 k][64 d]
      int g = tid + i * 256;
      int kk = g >> 3, dh = g & 7;
      gload_lds16(Kp + (bS + k0 + kk) * DMODEL + h * 64 + ((dh ^ (kk & 7)) << 3),
                  (char*)&Ks[nb][0] + g * 16);
    }
    #pragma unroll
    for (int i = 0; i < 2; ++i) {       // V^T tile [64 d][64 k]
      int g = tid + i * 256;
      int dd = g >> 3, kh = g & 7;
      gload_lds16(VpT + ((size_t)(bh * 64 + dd)) * S_LEN + k0 + ((kh ^ (dd & 7)) << 3),
                  (char*)&VTs[nb][0] + g * 16);
    }
  };

  stage(0, 0);
  __syncthreads();

  constexpr int NT = S_LEN / 64;
  for (int t = 0; t < NT; ++t) {
    const int cur = t & 1;
    if (t + 1 < NT) stage((t + 1) * 64, cur ^ 1);

    // ---- QK^T: ST[k][q] - 16, 2 chunks of 32 k ----
    f32x16 c0, c1;
    #pragma unroll
    for (int r = 0; r < 16; ++r) { c0[r] = -16.f; c1[r] = -16.f; }
    const u16* ksp = &Ks[cur][0];
    __builtin_amdgcn_s_setprio(1);
    #pragma unroll
    for (int dk = 0; dk < 4; ++dk) {
      short8 a0 = *(const short8*)&ksp[((l31) * 64 + dk * 16 + hi1 * 8) ^ ((l31 & 7) << 3)];
      short8 a1 = *(const short8*)&ksp[((32 + l31) * 64 + dk * 16 + hi1 * 8) ^ ((l31 & 7) << 3)];
      c0 = __builtin_amdgcn_mfma_f32_32x32x16_bf16(a0, qf[dk], c0, 0, 0, 0);
      c1 = __builtin_amdgcn_mfma_f32_32x32x16_bf16(a1, qf[dk], c1, 0, 0, 0);
    }
    __builtin_amdgcn_s_setprio(0);

    // ---- mask (register r holds k = (r&3) + 8*(r>>2) + 4*hi1 [+32 for c1]) ----
    u64 mw = mb[(size_t)(wq0 + l31) * 32 + t];
    bool allone = __all((long long)mw == -1LL);
    if (!allone) {
      #pragma unroll
      for (int r = 0; r < 16; ++r) {
        int k0i = (r & 3) + 8 * (r >> 2) + 4 * hi1;
        c0[r] = ((mw >> k0i) & 1) ? c0[r] : NEGL2;
        c1[r] = ((mw >> (k0i + 32)) & 1) ? c1[r] : NEGL2;
      }
    }

    // ---- static-max softmax: p = 2^(s-16); accumulate lsum ----
    float ls = 0.f;
    #pragma unroll
    for (int r = 0; r < 16; ++r) { float p = EXP2(c0[r]); c0[r] = p; ls += p; }
    #pragma unroll
    for (int r = 0; r < 16; ++r) { float p = EXP2(c1[r]); c1[r] = p; ls += p; }
    lsum += ls;

    // ---- pack P to bf16 word-pairs ----
    u32 Wp[2][8];
    #pragma unroll
    for (int i = 0; i < 8; ++i) {
      Wp[0][i] = cvtpk(c0[2 * i], c0[2 * i + 1]);
      Wp[1][i] = cvtpk(c1[2 * i], c1[2 * i + 1]);
    }

    // ---- PV: xacc[dt] += V^T(frag) * P^T(frag), 4 k-slices of 16 ----
    const u16* vtp = &VTs[cur][0];
    __builtin_amdgcn_s_setprio(1);
    #pragma unroll
    for (int ks16 = 0; ks16 < 4; ++ks16) {
      const int kc = ks16 >> 1, ks = ks16 & 1;
      // B-fragment: lane (q=l31, hi1) needs P[q][ks16*16 + hi1*8 + j]
      u32 wa0 = Wp[kc][ks * 4 + 0], wb0 = Wp[kc][ks * 4 + 2];
      u32 wa1 = Wp[kc][ks * 4 + 1], wb1 = Wp[kc][ks * 4 + 3];
      plswap(wa0, wb0);   // wa0 = word01, wb0 = word45 (per-lane correct halves)
      plswap(wa1, wb1);
      u32x4 pw; pw.x = wa0; pw.y = wa1; pw.z = wb0; pw.w = wb1;
      short8 pfrag = __builtin_bit_cast(short8, pw);
      #pragma unroll
      for (int dt = 0; dt < 2; ++dt) {
        int d = dt * 32 + l31;
        short8 vf = *(const short8*)&vtp[(d * 64 + ks16 * 16 + hi1 * 8) ^ ((d & 7) << 3)];
        xacc[dt] = __builtin_amdgcn_mfma_f32_32x32x16_bf16(vf, pfrag, xacc[dt], 0, 0, 0);
      }
    }
    __builtin_amdgcn_s_setprio(0);
    __syncthreads();
  }

  // ---- normalize + store: lane holds X^T[d = dt*32 + crow(r,hi1)][q = wq0+l31] ----
  lsum += __shfl_xor(lsum, 32);
  float inv = 1.0f / lsum;
  u16* xb = X + (bS + wq0 + l31) * DMODEL + h * 64;
  #pragma unroll
  for (int dt = 0; dt < 2; ++dt)
    #pragma unroll
    for (int m = 0; m < 4; ++m) {
      ushort4 o;
      o.x = f2bf(xacc[dt][m * 4 + 0] * inv);
      o.y = f2bf(xacc[dt][m * 4 + 1] * inv);
      o.z = f2bf(xacc[dt][m * 4 + 2] * inv);
      o.w = f2bf(xacc[dt][m * 4 + 3] * inv);
      *(ushort4*)(xb + dt * 32 + m * 8 + hi1 * 4) = o;
    }
}

extern "C" void kernel_launch(void* const* d_in, const int* in_sizes, int n_in,
                              void* d_out, int out_size, void* d_ws, size_t ws_size,
                              hipStream_t stream) {
  const float* q  = (const float*)d_in[0];
  const float* k  = (const float*)d_in[1];
  const float* v  = (const float*)d_in[2];
  const int* mask = (const int*)d_in[3];
  const float* wq = (const float*)d_in[4];
  const float* bq = (const float*)d_in[5];
  const float* wk = (const float*)d_in[6];
  const float* bk = (const float*)d_in[7];
  const float* wv = (const float*)d_in[8];
  const float* bv = (const float*)d_in[9];
  const float* wo = (const float*)d_in[10];
  const float* bo = (const float*)d_in[11];

  char* ws = (char*)d_ws;
  u16* wqb = (u16*)(ws + 0x000000);
  u16* wkb = (u16*)(ws + 0x200000);
  u16* wvb = (u16*)(ws + 0x400000);
  u16* wob = (u16*)(ws + 0x600000);
  u64* mbp = (u64*)(ws + 0x800000);
  u16* Qp  = (u16*)(ws + 0x880000);
  u16* Kp  = (u16*)(ws + 0x1880000);
  u16* Abv = (u16*)(ws + 0x2880000);   // bf16 v-input scratch
  u16* Xp  = (u16*)(ws + 0x3880000);   // q-input scratch pre-attn, then attn out
  u16* VpT = (u16*)(ws + 0x4880000);   // end 0x5880000 = 92.7 MB

  const float QSCALE = 0.125f * 1.44269504088896340736f;  // fold 1/sqrt(64) * log2(e)
  u16* Abk = (u16*)d_out;   // k-input scratch: d_out fully overwritten by final GEMM
  u16* Abq = Xp;            // dead by the time attn writes Xp

  prep_kernel<<<dim3(1024, 5), 256, 0, stream>>>(wq, wk, wv, wo, wqb, wkb, wvb, wob,
                                                 mask, mbp);
  cvt_a3_kernel<<<dim3(8192, 3), 256, 0, stream>>>(v, k, q, Abv, Abk, Abq);

  gemm_proj3_kernel<<<dim3(64, 8, 3), 256, 0, stream>>>(
      Abv, Abk, Abq, wvb, wkb, wqb, bv, bk, bq, VpT, Kp, Qp, QSCALE);

  attn_kernel<<<1024, 256, 0, stream>>>(Qp, Kp, VpT, mbp, Xp);
  gemm_out_kernel<<<dim3(64, 8), 256, 0, stream>>>(Xp, wob, bo, (float*)d_out);
}